// Round 5
// baseline (84.687 us; speedup 1.0000x reference)
//
#include <hip/hip_runtime.h>
#include <cmath>

// Problem constants (fixed by the reference's init kwargs):
//   POS_FREQS=31, W_MIN=0.1, W_MAX=1.0, PATCH=16 -> grid H=64 (row 63 padded), W=32
//   batch_triangles: [64,128,3,2] f32, lengths: [64] i32
//   outputs: mag [64,1,64,32] f32 then phase [64,1,64,32] f32, concatenated flat.
#define BB     64
#define MAXN   128
#define HH     64
#define WW     32
#define NFREQ  (HH*WW)      // 2048
#define BLK    256
#define PCHUNKS 4           // each thread handles 2 points: p and p+1024
#define TRI_CHUNK 16
#define QQ     (MAXN/TRI_CHUNK) // 8 triangle chunks
// workspace: float2 partial[QQ][BB][NFREQ] = 8*64*2048*8 B = 8 MB

// sin(2*pi*x), cos(2*pi*x) via hardware v_sin_f32/v_cos_f32 (input in
// REVOLUTIONS, reduced to [0,1) with v_fract_f32 first).
__device__ __forceinline__ void sincos_2pi(float x, float* s, float* c) {
    float r = __builtin_amdgcn_fractf(x);
    *s = __builtin_amdgcn_sinf(r);
    *c = __builtin_amdgcn_cosf(r);
}

// One (point, triangle) evaluation in the rotated frame:
//   E_x = exp(-2*pi*i*t_x), t_q = U*xq+V*yq, t_r = t_q+U_, t_s = t_r+V_
//   normal: part2*phase = -U_*E_s + S*E_r - V_*E_q
// Special branches re-derived in the same frame (see comments).
__device__ __forceinline__ void eval_tri(
    float U, float V, float4 A, float4 Bv, float& accR, float& accI,
    float TWOPI, float FOUR_PI2)
{
    const float xq = A.x,  yq = A.y,  e1x = A.z, e1y = A.w;
    const float e2x = Bv.x, e2y = Bv.y, area = Bv.z;

    // Mask-determining quantities: plain mul/mul/add (no FMA contraction)
    // to reproduce the reference's exact-zero pattern.
    const float U_ = __fadd_rn(__fmul_rn(U, e1x), __fmul_rn(V, e1y));
    const float V_ = __fadd_rn(__fmul_rn(U, e2x), __fmul_rn(V, e2y));
    const float S  = __fadd_rn(U_, V_);

    const bool uz = (U_ == 0.0f);
    const bool vz = (V_ == 0.0f);

    if (uz && vz) {
        accR += area;            // zero_mask: FT = area (real); padding adds 0
        return;
    }

    // Exponential args (not mask-relevant; fused math fine).
    const float t_q = U * xq + V * yq;
    const float t_r = t_q + U_;          // exact when U_==0
    const float t_s = t_r + V_;          // exact when V_==0

    float s_q, c_q, s_r, c_r, s_s, c_s;
    sincos_2pi(t_q, &s_q, &c_q);
    sincos_2pi(t_r, &s_r, &c_r);
    sincos_2pi(t_s, &s_s, &c_s);

    float p1, re, im;
    if (S == 0.0f) {
        // diag: part2*phase = E_r + (j*2pi*U_ - 1)*E_q
        p1 = -__builtin_amdgcn_rcpf(FOUR_PI2 * U_ * U_);
        re = c_r + TWOPI * U_ * s_q - c_q;
        im = -s_r + TWOPI * U_ * c_q + s_q;
    } else if (uz) {
        // u_mask: part2*phase = E_s + (j*2pi*V_ - 1)*E_q   (t_s == t_q+V_)
        p1 = -__builtin_amdgcn_rcpf(FOUR_PI2 * V_ * V_);
        re = c_s + TWOPI * V_ * s_q - c_q;
        im = -s_s + TWOPI * V_ * c_q + s_q;
    } else if (vz) {
        // v_mask: part2*phase = (j*2pi*U_ + 1)*E_r - E_q
        p1 = __builtin_amdgcn_rcpf(FOUR_PI2 * U_ * U_);
        re = c_r + TWOPI * U_ * s_r - c_q;
        im = TWOPI * U_ * c_r - s_r + s_q;
    } else {
        // normal: part2*phase = -U_*E_s + S*E_r - V_*E_q
        p1 = __builtin_amdgcn_rcpf(FOUR_PI2 * U_ * V_ * S);
        re = -U_ * c_s + S * c_r - V_ * c_q;
        im =  U_ * s_s - S * s_r + V_ * s_q;
    }

    const float k = 2.0f * area * p1;
    accR += k * re;
    accI += k * im;
}

__global__ __launch_bounds__(BLK) void poly_cft_partial(
    const float* __restrict__ tris,    // [64,128,3,2]
    const int*   __restrict__ lengths, // [64]
    float2*      __restrict__ ws)      // [QQ][BB][NFREQ] partial sums
{
    __shared__ float4 sA[TRI_CHUNK];  // xq, yq, e1x=xr-xq, e1y=yr-yq
    __shared__ float4 sB[TRI_CHUNK];  // e2x=xs-xr, e2y=ys-yr, area, unused
    __shared__ float  s_posw[31];

    const int pc = blockIdx.x;                 // 0..3 point chunk
    const int q  = blockIdx.y;                 // 0..7 triangle chunk
    const int b  = blockIdx.z;                 // 0..63 batch elem
    const int p0 = (pc << 8) | threadIdx.x;    // 0..1023  (h = 0..31)
    const int p1 = p0 + 1024;                  // h = 32..63, same w
    const int h0 = p0 >> 5;                    // 0..31
    const int w  = p0 & 31;

    const int N   = lengths[b];
    const int n0  = q * TRI_CHUNK;
    const int cnt = min(n0 + TRI_CHUNK, N) - n0;   // may be <= 0

    const size_t base = ((size_t)q * BB + b) * NFREQ;

    // Entire chunk out of range: write zeros, exit (block-uniform branch).
    if (cnt <= 0) {
        ws[base + p0] = make_float2(0.0f, 0.0f);
        ws[base + p1] = make_float2(0.0f, 0.0f);
        return;
    }

    // Frequency grid values, matching numpy exactly:
    //   g = (1.0/0.1)**(1/30) in double; pos_w[k] = float32(0.1 * g**k)
    if (threadIdx.x < 31) {
        double g = pow(10.0, 1.0 / 30.0);
        s_posw[threadIdx.x] = (float)(0.1 * pow(g, (double)threadIdx.x));
    }

    // Stage TRI_CHUNK triangles; pad invalid slots with degenerate zeros
    // (U_=V_=0 -> zero-mask branch -> contributes exactly area=0).
    if (threadIdx.x < TRI_CHUNK) {
        if ((int)threadIdx.x < cnt) {
            const float* t = tris + ((size_t)b * MAXN + n0 + threadIdx.x) * 6;
            float xq = t[0], yq = t[1];
            float xr = t[2], yr = t[3];
            float xs = t[4], ys = t[5];
            float det  = xq * (yr - ys) + xr * (ys - yq) + xs * (yq - yr);
            float area = fabsf(0.5f * det);
            sA[threadIdx.x] = make_float4(xq, yq, xr - xq, yr - yq);
            sB[threadIdx.x] = make_float4(xs - xr, ys - yr, area, 0.0f);
        } else {
            sA[threadIdx.x] = make_float4(0.0f, 0.0f, 0.0f, 0.0f);
            sB[threadIdx.x] = make_float4(0.0f, 0.0f, 0.0f, 0.0f);
        }
    }
    __syncthreads();

    // Point 0: U0 = Wx[h0] (negative freqs + zero row); point 1: U1 = Wx[h0+32]
    const float U0 = (h0 < 31) ? -s_posw[30 - h0] : 0.0f;
    const float U1 = (h0 < 31) ?  s_posw[h0]      : 0.0f;  // h=63 pad row -> 0
    const float V  = (w == 0) ? 0.0f : s_posw[w - 1];

    // float32 constants exactly as the reference builds them:
    const float PI_F     = 3.14159274101257324f;   // np.float32(np.pi)
    const float TWOPI    = 6.28318548202514648f;   // 2*pi_f
    const float FOUR_PI2 = (4.0f * PI_F) * PI_F;   // np.float32(4)*pi*pi

    float acc0R = 0.0f, acc0I = 0.0f;
    float acc1R = 0.0f, acc1I = 0.0f;

    // Fixed trip count (uniform block cost); two independent points per
    // thread give two independent dependency chains for latency hiding.
#pragma unroll 2
    for (int n = 0; n < TRI_CHUNK; ++n) {
        const float4 A  = sA[n];
        const float4 Bv = sB[n];
        eval_tri(U0, V, A, Bv, acc0R, acc0I, TWOPI, FOUR_PI2);
        eval_tri(U1, V, A, Bv, acc1R, acc1I, TWOPI, FOUR_PI2);
    }

    ws[base + p0] = make_float2(acc0R, acc0I);
    ws[base + p1] = make_float2(acc1R, acc1I);
}

__global__ __launch_bounds__(BLK) void poly_cft_finalize(
    const float2* __restrict__ ws,   // [QQ][BB][NFREQ]
    float*        __restrict__ out)  // [2*64*2048]
{
    const int idx = blockIdx.x * BLK + threadIdx.x;  // 0..131071
    const int b = idx >> 11;
    const int p = idx & (NFREQ - 1);
    const int h = p >> 5;

    float accR = 0.0f, accI = 0.0f;
#pragma unroll
    for (int q = 0; q < QQ; ++q) {
        float2 v = ws[((size_t)q * BB + b) * NFREQ + p];
        accR += v.x;
        accI += v.y;
    }

    if (h == 63) { accR = 0.0f; accI = 0.0f; }   // pad row

    const float m2 = __fadd_rn(__fmul_rn(accR, accR), __fmul_rn(accI, accI));
    float mag, ph;
    if (m2 == 0.0f) {
        mag = 0.0f;
        ph  = atan2f(accI, 1.0f);   // angle(0) = 0 semantics
    } else {
        mag = log1pf(sqrtf(m2));
        ph  = atan2f(accI, accR);
    }

    out[idx]              = mag;   // mag block [64,1,64,32]
    out[BB * NFREQ + idx] = ph;    // phase block follows
}

extern "C" void kernel_launch(void* const* d_in, const int* in_sizes, int n_in,
                              void* d_out, int out_size, void* d_ws, size_t ws_size,
                              hipStream_t stream) {
    const float* tris    = (const float*)d_in[0]; // [64,128,3,2] f32
    const int*   lengths = (const int*)d_in[1];   // [64] i32
    float*       out     = (float*)d_out;         // [2*64*2048] f32
    float2*      partial = (float2*)d_ws;         // 8 MB of scratch

    poly_cft_partial<<<dim3(PCHUNKS, QQ, BB), dim3(BLK), 0, stream>>>(tris, lengths, partial);
    poly_cft_finalize<<<dim3(BB * NFREQ / BLK), dim3(BLK), 0, stream>>>(partial, out);
}

// Round 6
// 79.172 us; speedup vs baseline: 1.0697x; 1.0697x over previous
//
#include <hip/hip_runtime.h>
#include <cmath>

// Problem constants (fixed by the reference's init kwargs):
//   POS_FREQS=31, W_MIN=0.1, W_MAX=1.0, PATCH=16 -> grid H=64 (row 63 padded), W=32
//   batch_triangles: [64,128,3,2] f32, lengths: [64] i32
//   outputs: mag [64,1,64,32] f32 then phase [64,1,64,32] f32, concatenated flat.
#define BB     64
#define MAXN   128
#define HH     64
#define WW     32
#define NFREQ  (HH*WW)      // 2048
#define BLK    256
#define PCHUNKS (NFREQ/BLK) // 8 point-chunks per batch elem
#define TRI_CHUNK 16
#define QQ     (MAXN/TRI_CHUNK) // 8 triangle chunks
// workspace: float2 partial[QQ][BB][NFREQ] = 8*64*2048*8 B = 8 MB

// sin(2*pi*x), cos(2*pi*x) via hardware v_sin_f32/v_cos_f32 (input in
// REVOLUTIONS, reduced to [0,1) with v_fract_f32 first).
__device__ __forceinline__ void sincos_2pi(float x, float* s, float* c) {
    float r = __builtin_amdgcn_fractf(x);
    *s = __builtin_amdgcn_sinf(r);
    *c = __builtin_amdgcn_cosf(r);
}

// Fully BRANCHLESS (point, triangle) evaluation.
// Rotated frame: E_x = exp(-2*pi*i*t_x), t_q = U*xq+V*yq, t_r = t_q+U_,
// t_s = t_r+V_.  All four reference cases share:
//   re =  A*c_s + B*c_r + C*c_q + D*s_r + E*s_q
//   im = -A*s_s - B*s_r - C*s_q + D*c_r + E*c_q
// with k = sgn*area/(4pi^2*den):
//   normal: A=-U_, B=S,  C=-V_, D=0,     E=0;     den=U_*V_*S, sgn=+2
//   diag  : A=0,   B=1,  C=-1,  D=0,     E=2piU_; den=U_^2,    sgn=-2
//   u_mask: A=1,   B=0,  C=-1,  D=0,     E=2piV_; den=V_^2,    sgn=-2
//   v_mask: A=0,   B=1,  C=-1,  D=2piU_, E=0;     den=U_^2,    sgn=+2
//   zero  : k=0, add area directly.
__device__ __forceinline__ void eval_tri(
    float U, float V, float4 A4, float4 B4, float& accR, float& accI,
    float TWOPI, float FOUR_PI2)
{
    const float xq = A4.x,  yq = A4.y,  e1x = A4.z, e1y = A4.w;
    const float e2x = B4.x, e2y = B4.y, area = B4.z;

    // Mask-determining quantities: plain mul/mul/add (no FMA contraction)
    // to reproduce the reference's exact-zero pattern.
    const float U_ = __fadd_rn(__fmul_rn(U, e1x), __fmul_rn(V, e1y));
    const float V_ = __fadd_rn(__fmul_rn(U, e2x), __fmul_rn(V, e2y));
    const float S  = __fadd_rn(U_, V_);

    const bool uz   = (U_ == 0.0f);
    const bool vz   = (V_ == 0.0f);
    const bool sz   = (S  == 0.0f);
    const bool zero = uz && vz;
    const bool diag = sz && !zero;      // uz -> (sz<->vz), so cases exclusive
    const bool u_m  = uz && !zero;
    const bool v_m  = vz && !zero;
    const bool nrm  = !(uz || vz || sz);

    // Exponential args (not mask-relevant; FMA fine). t_r/t_s exact when
    // U_/V_ are exactly 0 (adding exact zero), which the special cases need.
    const float t_q = U * xq + V * yq;
    const float t_r = t_q + U_;
    const float t_s = t_r + V_;

    float s_q, c_q, s_r, c_r, s_s, c_s;
    sincos_2pi(t_q, &s_q, &c_q);
    sincos_2pi(t_r, &s_r, &c_r);
    sincos_2pi(t_s, &s_s, &c_s);

    const float twU = TWOPI * U_;
    const float twV = TWOPI * V_;

    const float Ac = nrm ? -U_ : (u_m ? 1.0f : 0.0f);
    const float Bc = nrm ?  S  : ((diag || v_m) ? 1.0f : 0.0f);
    const float Cc = nrm ? -V_ : -1.0f;
    const float Dc = v_m  ? twU : 0.0f;
    const float Ec = diag ? twU : (u_m ? twV : 0.0f);

    const float d1  = u_m ? V_ : U_;
    const float den = nrm ? (U_ * V_) * S : d1 * d1;
    const float p1  = __builtin_amdgcn_rcpf(FOUR_PI2 * den);
    const float sgn = (diag || u_m) ? -2.0f : 2.0f;
    const float k   = zero ? 0.0f : sgn * area * p1;   // cndmask kills inf path

    const float re =  Ac * c_s + Bc * c_r + Cc * c_q + Dc * s_r + Ec * s_q;
    const float im = -(Ac * s_s + Bc * s_r + Cc * s_q) + Dc * c_r + Ec * c_q;

    accR = fmaf(k, re, accR) + (zero ? area : 0.0f);
    accI = fmaf(k, im, accI);
}

__global__ __launch_bounds__(BLK) void poly_cft_partial(
    const float* __restrict__ tris,    // [64,128,3,2]
    const int*   __restrict__ lengths, // [64]
    float2*      __restrict__ ws)      // [QQ][BB][NFREQ] partial sums
{
    __shared__ float4 sA[TRI_CHUNK];  // xq, yq, e1x=xr-xq, e1y=yr-yq
    __shared__ float4 sB[TRI_CHUNK];  // e2x=xs-xr, e2y=ys-yr, area, unused
    __shared__ float  s_posw[31];

    const int pc = blockIdx.x;                 // 0..7 point chunk
    const int q  = blockIdx.y;                 // 0..7 triangle chunk
    const int b  = blockIdx.z;                 // 0..63 batch elem
    const int p  = (pc << 8) | threadIdx.x;    // 0..2047 freq point
    const int h  = p >> 5;
    const int w  = p & 31;

    const int N   = lengths[b];
    const int n0  = q * TRI_CHUNK;
    const int cnt = min(n0 + TRI_CHUNK, N) - n0;   // may be <= 0

    // Entire chunk out of range: nothing to do — finalize only reads chunks
    // q < ceil(N/TRI_CHUNK), so no zero-write is needed.
    if (cnt <= 0) return;

    // Frequency grid values, matching numpy exactly:
    //   g = (1.0/0.1)**(1/30) in double; pos_w[k] = float32(0.1 * g**k)
    if (threadIdx.x < 31) {
        double g = pow(10.0, 1.0 / 30.0);
        s_posw[threadIdx.x] = (float)(0.1 * pow(g, (double)threadIdx.x));
    }

    // Stage TRI_CHUNK triangles; pad invalid slots with degenerate zeros
    // (U_=V_=0 -> zero case -> contributes exactly area=0).
    if (threadIdx.x < TRI_CHUNK) {
        if ((int)threadIdx.x < cnt) {
            const float* t = tris + ((size_t)b * MAXN + n0 + threadIdx.x) * 6;
            float xq = t[0], yq = t[1];
            float xr = t[2], yr = t[3];
            float xs = t[4], ys = t[5];
            float det  = xq * (yr - ys) + xr * (ys - yq) + xs * (yq - yr);
            float area = fabsf(0.5f * det);
            sA[threadIdx.x] = make_float4(xq, yq, xr - xq, yr - yq);
            sB[threadIdx.x] = make_float4(xs - xr, ys - yr, area, 0.0f);
        } else {
            sA[threadIdx.x] = make_float4(0.0f, 0.0f, 0.0f, 0.0f);
            sB[threadIdx.x] = make_float4(0.0f, 0.0f, 0.0f, 0.0f);
        }
    }
    __syncthreads();

    // U = Wx[h], V = Wy[w]
    float U;
    if (h < 31)       U = -s_posw[30 - h];
    else if (h == 31) U = 0.0f;
    else if (h < 63)  U = s_posw[h - 32];
    else              U = 0.0f;   // padded row (masked in finalize)
    const float V = (w == 0) ? 0.0f : s_posw[w - 1];

    // float32 constants exactly as the reference builds them:
    const float PI_F     = 3.14159274101257324f;   // np.float32(np.pi)
    const float TWOPI    = 6.28318548202514648f;   // 2*pi_f
    const float FOUR_PI2 = (4.0f * PI_F) * PI_F;   // np.float32(4)*pi*pi

    float accR = 0.0f, accI = 0.0f;

    // Fixed trip count + branchless body: the unrolled iterations are fully
    // independent instruction streams the scheduler can pipeline (the trans
    // ops and rcp are no longer trapped behind divergent branches).
#pragma unroll 4
    for (int n = 0; n < TRI_CHUNK; ++n) {
        eval_tri(U, V, sA[n], sB[n], accR, accI, TWOPI, FOUR_PI2);
    }

    ws[((size_t)q * BB + b) * NFREQ + p] = make_float2(accR, accI);
}

__global__ __launch_bounds__(BLK) void poly_cft_finalize(
    const float2* __restrict__ ws,   // [QQ][BB][NFREQ]
    const int*    __restrict__ lengths,
    float*        __restrict__ out)  // [2*64*2048]
{
    const int idx = blockIdx.x * BLK + threadIdx.x;  // 0..131071
    const int b = idx >> 11;
    const int p = idx & (NFREQ - 1);
    const int h = p >> 5;

    // Only chunks with work were written; loop bound is block-uniform
    // (b is constant within a 256-thread block).
    const int QN = (lengths[b] + TRI_CHUNK - 1) / TRI_CHUNK;

    float accR = 0.0f, accI = 0.0f;
    for (int q = 0; q < QN; ++q) {
        float2 v = ws[((size_t)q * BB + b) * NFREQ + p];
        accR += v.x;
        accI += v.y;
    }

    if (h == 63) { accR = 0.0f; accI = 0.0f; }   // pad row

    const float m2 = __fadd_rn(__fmul_rn(accR, accR), __fmul_rn(accI, accI));
    float mag, ph;
    if (m2 == 0.0f) {
        mag = 0.0f;
        ph  = atan2f(accI, 1.0f);   // angle(0) = 0 semantics
    } else {
        mag = log1pf(sqrtf(m2));
        ph  = atan2f(accI, accR);
    }

    out[idx]              = mag;   // mag block [64,1,64,32]
    out[BB * NFREQ + idx] = ph;    // phase block follows
}

extern "C" void kernel_launch(void* const* d_in, const int* in_sizes, int n_in,
                              void* d_out, int out_size, void* d_ws, size_t ws_size,
                              hipStream_t stream) {
    const float* tris    = (const float*)d_in[0]; // [64,128,3,2] f32
    const int*   lengths = (const int*)d_in[1];   // [64] i32
    float*       out     = (float*)d_out;         // [2*64*2048] f32
    float2*      partial = (float2*)d_ws;         // 8 MB of scratch

    poly_cft_partial<<<dim3(PCHUNKS, QQ, BB), dim3(BLK), 0, stream>>>(tris, lengths, partial);
    poly_cft_finalize<<<dim3(BB * NFREQ / BLK), dim3(BLK), 0, stream>>>(partial, lengths, out);
}